// Round 10
// baseline (514.439 us; speedup 1.0000x reference)
//
#include <hip/hip_runtime.h>

typedef unsigned short ushort_t;
typedef __attribute__((ext_vector_type(8))) short short8;
typedef __attribute__((ext_vector_type(4))) float f32x4;

#define N_NODES 50000
#define NBASE   4
#define N_EDGE  320000
#define DM_BLOCKS 2048
#define N_GROUPS (N_EDGE / 8)
#define SCAN_BLOCKS 49          // 49*1024 = 50176 >= 50000
#define LDSB_STRIDE 136         // 128 + 8 ushorts pad
#define FILL_B (N_EDGE / 256)   // 1250
#define X0_B   (N_NODES * 128 / 256)

// canonical fp32 small-tensor layout (element offsets)
#define C_COMP1 0
#define C_COMP2 100
#define C_BIAS1 200
#define C_BIAS2 328
#define C_REL   456
#define C_EBIAS 1992
#define C_TOTAL 2120

__device__ __forceinline__ float bf2f(ushort_t u) {
    union { unsigned int i; float f; } v; v.i = ((unsigned int)u) << 16; return v.f;
}
__device__ __forceinline__ ushort_t f2bf(float f) {
    union { float f; unsigned int i; } v; v.f = f;
    unsigned int u = v.i;
    u = (u + 0x7FFFu + ((u >> 16) & 1u)) >> 16;   // RNE
    return (ushort_t)u;
}
__device__ __forceinline__ float readf(const void* p, int i, int isbf) {
    return isbf ? bf2f(((const ushort_t*)p)[i]) : ((const float*)p)[i];
}
__device__ __forceinline__ float softplus(float x) {
    if (x > 20.f) return x;
    if (x < -20.f) return expf(x);
    return log1pf(expf(x));
}

// Fused: block 0 = dtype-detect + canonicalize smalls; blocks >=1 = degree count.
__global__ void k_prepcnt(const ushort_t* __restrict__ emb, int* __restrict__ flag,
                          const void* comp1, const void* comp2, const void* b1, const void* b2,
                          const void* rel, const void* eb, float* __restrict__ canon,
                          const int* __restrict__ ei, int* __restrict__ cnt) {
    if (blockIdx.x == 0) {
        __shared__ int c;
        if (threadIdx.x == 0) c = 0;
        __syncthreads();
        int e = (emb[threadIdx.x] >> 7) & 0xFF;
        if (e >= 100 && e <= 126) atomicAdd(&c, 1);
        __syncthreads();
        if (threadIdx.x == 0) *flag = (c >= 200) ? 1 : 0;  // 1 = bf16 inputs
        int isbf = (c >= 200) ? 1 : 0;
        for (int i = threadIdx.x; i < C_TOTAL; i += blockDim.x) {
            float v;
            if      (i < C_COMP2) v = readf(comp1, i - C_COMP1, isbf);
            else if (i < C_BIAS1) v = readf(comp2, i - C_COMP2, isbf);
            else if (i < C_BIAS2) v = readf(b1,    i - C_BIAS1, isbf);
            else if (i < C_REL)   v = readf(b2,    i - C_BIAS2, isbf);
            else if (i < C_EBIAS) v = readf(rel,   i - C_REL,   isbf);
            else                  v = readf(eb,    i - C_EBIAS, isbf);
            canon[i] = v;
        }
    } else {
        int e = (blockIdx.x - 1) * 256 + threadIdx.x;
        if (e < N_EDGE) atomicAdd(&cnt[ei[N_EDGE + e]], 1);
    }
}

// scan stage A: per-block LDS scan + last-finishing block scans the 49 block sums.
__global__ void k_scanA(const int* __restrict__ cnt, int* __restrict__ ptr,
                        int* __restrict__ bsum, int* __restrict__ boff,
                        int* __restrict__ ticket) {
    __shared__ int s[1024];
    __shared__ int lastf;
    int t = threadIdx.x;
    int i = blockIdx.x * 1024 + t;
    int v = (i < N_NODES) ? cnt[i] : 0;
    s[t] = v;
    __syncthreads();
    for (int off = 1; off < 1024; off <<= 1) {
        int u = (t >= off) ? s[t - off] : 0;
        __syncthreads();
        s[t] += u;
        __syncthreads();
    }
    if (i < N_NODES) ptr[i] = s[t] - v;          // local exclusive
    if (t == 1023) bsum[blockIdx.x] = s[1023];
    __threadfence();
    if (t == 0) lastf = (atomicAdd(ticket, 1) == SCAN_BLOCKS - 1);
    __syncthreads();
    if (lastf && t < 64) {
        __threadfence();                          // acquire other blocks' bsum
        int w = (t < SCAN_BLOCKS) ? bsum[t] : 0;
        int orig = w;
        #pragma unroll
        for (int off = 1; off < 64; off <<= 1) {
            int u = __shfl_up(w, off);
            if (t >= off) w += u;
        }
        boff[t] = w - orig;                       // exclusive block offsets
    }
}

// scan stage B: add block offsets -> final ptr + cursor
__global__ void k_scan3(int* __restrict__ ptr, int* __restrict__ cursor,
                        const int* __restrict__ boff) {
    int t = threadIdx.x;
    int i = blockIdx.x * 1024 + t;
    if (i < N_NODES) {
        int p = ptr[i] + boff[blockIdx.x];
        ptr[i] = p;
        cursor[i] = p;
    }
    if (blockIdx.x == 0 && t == 0) ptr[N_NODES] = N_EDGE;
}

// Fused: blocks [0,FILL_B) = CSR fill; [FILL_B,+512) = repack bases; rest = x0.
__global__ void k_fillinit(const int* __restrict__ ei, const int* __restrict__ et,
                           int* __restrict__ cursor, unsigned int* __restrict__ packed,
                           const void* __restrict__ bases1, ushort_t* __restrict__ btK1,
                           const void* __restrict__ bases2, ushort_t* __restrict__ btK2,
                           const void* __restrict__ emb, const float* __restrict__ canon,
                           ushort_t* __restrict__ x, const int* __restrict__ flag) {
    int bid = blockIdx.x;
    if (bid < FILL_B) {
        int e = bid * 256 + threadIdx.x;
        int dst = ei[N_EDGE + e];
        int pos = atomicAdd(&cursor[dst], 1);
        packed[pos] = (unsigned int)(ei[e] & 0xFFFF) | ((unsigned int)et[e] << 16);
    } else if (bid < FILL_B + 512) {
        int isbf = *flag;
        int rb = bid - FILL_B;
        const void* bases = (rb < 256) ? bases1 : bases2;
        ushort_t* btK = (rb < 256) ? btK1 : btK2;
        int idx = (rb & 255) * 256 + threadIdx.x;
        int b = idx >> 14, i = (idx >> 7) & 127, o = idx & 127;
        btK[(size_t)o * 512 + (b << 7) + i] = f2bf(readf(bases, idx, isbf));
    } else {
        int isbf = *flag;
        int i = (bid - FILL_B - 512) * 256 + threadIdx.x;
        if (i < N_NODES * 128) {
            float v = readf(emb, i, isbf) + canon[C_EBIAS + (i & 127)];
            x[i] = f2bf(fmaxf(v, 0.f));
        }
    }
}

// ---------------- pre-projection aggregate (x-space gather) ----------------
// y[m, b*128+o] = sum_{e in CSR[m]} comp[r_e, b] * x[src_e, o]    (bf16 out)
// ONE WAVE PER NODE, lane owns a packed bf16x2 column pair, 8-edge unroll.
__global__ void k_agg2(const ushort_t* __restrict__ x, const int* __restrict__ ptr,
                       const unsigned int* __restrict__ packed, const float* __restrict__ compf,
                       ushort_t* __restrict__ y) {
    __shared__ float sc[100];
    int tid = threadIdx.x;                  // 256 = 4 waves -> 4 nodes/block
    for (int i = tid; i < 100; i += 256) sc[i] = compf[i];
    __syncthreads();
    int m = blockIdx.x * 4 + (tid >> 6);
    int lane = tid & 63;
    int o2 = lane << 1;
    int beg = ptr[m], end = ptr[m + 1];
    float l0 = 0.f, l1 = 0.f, l2 = 0.f, l3 = 0.f;
    float h0 = 0.f, h1 = 0.f, h2 = 0.f, h3 = 0.f;
    int i = beg;
    for (; i + 8 <= end; i += 8) {
        unsigned int p[8], wv[8];
        #pragma unroll
        for (int j = 0; j < 8; ++j) p[j] = packed[i + j];
        #pragma unroll
        for (int j = 0; j < 8; ++j)
            wv[j] = *(const unsigned int*)(x + (size_t)(p[j] & 0xFFFFu) * 128 + o2);
        #pragma unroll
        for (int j = 0; j < 8; ++j) {
            const float* c = sc + (p[j] >> 16) * 4;
            float vl = bf2f((ushort_t)wv[j]), vh = bf2f((ushort_t)(wv[j] >> 16));
            l0 += c[0] * vl; l1 += c[1] * vl; l2 += c[2] * vl; l3 += c[3] * vl;
            h0 += c[0] * vh; h1 += c[1] * vh; h2 += c[2] * vh; h3 += c[3] * vh;
        }
    }
    for (; i < end; ++i) {
        unsigned int p0 = packed[i];
        unsigned int w0 = *(const unsigned int*)(x + (size_t)(p0 & 0xFFFFu) * 128 + o2);
        const float* c0 = sc + (p0 >> 16) * 4;
        float vl = bf2f((ushort_t)w0), vh = bf2f((ushort_t)(w0 >> 16));
        l0 += c0[0] * vl; l1 += c0[1] * vl; l2 += c0[2] * vl; l3 += c0[3] * vl;
        h0 += c0[0] * vh; h1 += c0[1] * vh; h2 += c0[2] * vh; h3 += c0[3] * vh;
    }
    unsigned int* yp = (unsigned int*)(y + (size_t)m * 512 + o2);
    yp[0]   = (unsigned int)f2bf(l0) | ((unsigned int)f2bf(h0) << 16);
    yp[64]  = (unsigned int)f2bf(l1) | ((unsigned int)f2bf(h1) << 16);
    yp[128] = (unsigned int)f2bf(l2) | ((unsigned int)f2bf(h2) << 16);
    yp[192] = (unsigned int)f2bf(l3) | ((unsigned int)f2bf(h3) << 16);
}

// ---------------- K=512 GEMM: xout = post(y @ W) ----------------
__global__ __launch_bounds__(256) void
k_gemm512(const ushort_t* __restrict__ y, const ushort_t* __restrict__ btK,
          const int* __restrict__ cnt, const float* __restrict__ canon,
          ushort_t* __restrict__ xout, int cbias, int dorelu) {
    __shared__ ushort_t bs[128 * LDSB_STRIDE];    // 34.8 KB
    int tid = threadIdx.x;
    int lane = tid & 63, w = tid >> 6;
    int r = lane & 15, q = lane >> 4;
    int m0 = blockIdx.x * 128;
    f32x4 acc[2][8] = {};
    int row0 = m0 + w * 32 + r;
    int row1 = row0 + 16;
    int cr0 = (row0 < N_NODES) ? row0 : (N_NODES - 1);
    int cr1 = (row1 < N_NODES) ? row1 : (N_NODES - 1);
    const ushort_t* ar0 = y + (size_t)cr0 * 512;
    const ushort_t* ar1 = y + (size_t)cr1 * 512;

    for (int c = 0; c < 4; ++c) {
        __syncthreads();
        {
            int o = tid >> 4;
            int j = (tid & 15) << 3;
            #pragma unroll
            for (int s = 0; s < 8; ++s, o += 16) {
                short8 v = *(const short8*)(btK + (size_t)o * 512 + c * 128 + j);
                *(short8*)(bs + o * LDSB_STRIDE + j) = v;
            }
        }
        __syncthreads();
        #pragma unroll
        for (int ksl = 0; ksl < 4; ++ksl) {
            int k0 = ksl * 32 + q * 8;
            short8 a0 = *(const short8*)(ar0 + c * 128 + k0);
            short8 a1 = *(const short8*)(ar1 + c * 128 + k0);
            #pragma unroll
            for (int t = 0; t < 8; ++t) {
                short8 b = *(const short8*)(bs + (t * 16 + r) * LDSB_STRIDE + k0);
                acc[0][t] = __builtin_amdgcn_mfma_f32_16x16x32_bf16(a0, b, acc[0][t], 0, 0, 0);
                acc[1][t] = __builtin_amdgcn_mfma_f32_16x16x32_bf16(a1, b, acc[1][t], 0, 0, 0);
            }
        }
    }
    #pragma unroll
    for (int i = 0; i < 2; ++i) {
        int rbase = m0 + w * 32 + i * 16 + (q << 2);
        float d[4];
        #pragma unroll
        for (int ii = 0; ii < 4; ++ii) {
            int rr = rbase + ii;
            d[ii] = fmaxf((float)cnt[(rr < N_NODES) ? rr : (N_NODES - 1)], 1.0f);
        }
        #pragma unroll
        for (int t = 0; t < 8; ++t) {
            int col = t * 16 + r;                 // D: col=lane&15, row=quad*4+reg
            float bb = canon[cbias + col];
            #pragma unroll
            for (int ii = 0; ii < 4; ++ii) {
                int rr = rbase + ii;
                if (rr < N_NODES) {
                    float v = acc[i][t][ii] / d[ii] + bb;
                    if (dorelu) v = fmaxf(v, 0.f);
                    xout[(size_t)rr * 128 + col] = f2bf(v);
                }
            }
        }
    }
}

// ---------------- DistMult + fused final reduce (last-block ticket) ----------------
__global__ void k_distmultF(const ushort_t* __restrict__ x2, const float* __restrict__ canon,
                            const int* __restrict__ ei, const int* __restrict__ et,
                            const int* __restrict__ neg, float* __restrict__ outp,
                            float* __restrict__ partials, int* __restrict__ ticket) {
    __shared__ float srel[1536];                  // 12 rel x 128, 6 KB
    __shared__ float s[3][4];
    __shared__ float fr[3][256];
    __shared__ int lastf;
    int tid = threadIdx.x;
    for (int i = tid; i < 1536; i += 256) srel[i] = canon[C_REL + i];
    __syncthreads();
    int lane = tid & 63;
    int g = lane >> 3;
    int l = lane & 7;
    int w = (blockIdx.x * blockDim.x + tid) >> 6;
    int nw = (DM_BLOCKS * 256) >> 6;
    float aL1 = 0.f, aL2 = 0.f, aA = 0.f;
    for (int gid = w; gid < N_GROUPS; gid += nw) {
        int e = gid * 8 + g;
        int h = ei[e], t = ei[N_EDGE + e], r = et[e], qn = neg[e];
        const ushort_t* ph = x2 + (size_t)h * 128 + l * 16;
        const ushort_t* pt = x2 + (size_t)t * 128 + l * 16;
        const ushort_t* pq = x2 + (size_t)qn * 128 + l * 16;
        const float*    pr = srel + r * 128 + l * 16;
        short8 h0 = *(const short8*)ph, h1 = *(const short8*)(ph + 8);
        short8 t0 = *(const short8*)pt, t1 = *(const short8*)(pt + 8);
        short8 q0 = *(const short8*)pq, q1 = *(const short8*)(pq + 8);
        float sp = 0.f, sn = 0.f;
        #pragma unroll
        for (int j = 0; j < 8; ++j) {
            float hv = bf2f(((const ushort_t*)&h0)[j]) * pr[j];
            sp += hv * bf2f(((const ushort_t*)&t0)[j]);
            sn += hv * bf2f(((const ushort_t*)&q0)[j]);
        }
        #pragma unroll
        for (int j = 0; j < 8; ++j) {
            float hv = bf2f(((const ushort_t*)&h1)[j]) * pr[8 + j];
            sp += hv * bf2f(((const ushort_t*)&t1)[j]);
            sn += hv * bf2f(((const ushort_t*)&q1)[j]);
        }
        sp += __shfl_down(sp, 4); sn += __shfl_down(sn, 4);
        sp += __shfl_down(sp, 2); sn += __shfl_down(sn, 2);
        sp += __shfl_down(sp, 1); sn += __shfl_down(sn, 1);
        if (l == 0) {
            outp[e] = sp;
            aL1 += softplus(-sp);
            aL2 += softplus(sn);
            aA  += (sp > sn) ? 1.0f : 0.0f;
        }
    }
    #pragma unroll
    for (int off = 32; off; off >>= 1) {
        aL1 += __shfl_down(aL1, off);
        aL2 += __shfl_down(aL2, off);
        aA  += __shfl_down(aA,  off);
    }
    int wl = tid >> 6;
    if (lane == 0) { s[0][wl] = aL1; s[1][wl] = aL2; s[2][wl] = aA; }
    __syncthreads();
    if (tid == 0) {
        float t0 = 0.f, t1 = 0.f, t2 = 0.f;
        for (int i = 0; i < 4; ++i) { t0 += s[0][i]; t1 += s[1][i]; t2 += s[2][i]; }
        partials[blockIdx.x * 3 + 0] = t0;
        partials[blockIdx.x * 3 + 1] = t1;
        partials[blockIdx.x * 3 + 2] = t2;
    }
    __threadfence();
    if (tid == 0) lastf = (atomicAdd(ticket, 1) == DM_BLOCKS - 1);
    __syncthreads();
    if (lastf) {
        __threadfence();                          // acquire all partials
        float t0 = 0.f, t1 = 0.f, t2 = 0.f;
        for (int i = tid; i < DM_BLOCKS; i += 256) {
            t0 += partials[i * 3 + 0];
            t1 += partials[i * 3 + 1];
            t2 += partials[i * 3 + 2];
        }
        fr[0][tid] = t0; fr[1][tid] = t1; fr[2][tid] = t2;
        __syncthreads();
        for (int st = 128; st; st >>= 1) {
            if (tid < st) {
                fr[0][tid] += fr[0][tid + st];
                fr[1][tid] += fr[1][tid + st];
                fr[2][tid] += fr[2][tid + st];
            }
            __syncthreads();
        }
        if (tid == 0) {
            float inv = 1.0f / (float)N_EDGE;
            outp[N_EDGE]     = 0.5f * (fr[0][0] * inv + fr[1][0] * inv);
            outp[N_EDGE + 1] = fr[2][0] * inv;
        }
    }
}

extern "C" void kernel_launch(void* const* d_in, const int* in_sizes, int n_in,
                              void* d_out, int out_size, void* d_ws, size_t ws_size,
                              hipStream_t stream) {
    const void* emb    = d_in[0];
    const void* ebias  = d_in[1];
    const void* bases1 = d_in[2];
    const void* comp1  = d_in[3];
    const void* bias1  = d_in[4];
    const void* bases2 = d_in[5];
    const void* comp2  = d_in[6];
    const void* bias2  = d_in[7];
    const void* rel    = d_in[8];
    const int*  ei     = (const int*)d_in[9];
    const int*  et     = (const int*)d_in[10];
    const int*  neg    = (const int*)d_in[11];
    float*      outp   = (float*)d_out;

    char* ws = (char*)d_ws;
    size_t off = 0;
    auto alloc = [&](size_t bytes) { char* p = ws + off; off += (bytes + 255) & ~(size_t)255; return p; };
    int*          flag   = (int*)alloc(256);
    float*        canon  = (float*)alloc((size_t)C_TOTAL * 4);
    int*          cnt    = (int*)alloc((size_t)N_NODES * 4 + 256);   // + tickets
    int*          tick   = cnt + N_NODES;                            // tick[0]=scan, tick[1]=dm
    int*          ptr    = (int*)alloc((size_t)(N_NODES + 1) * 4);
    int*          cursor = (int*)alloc((size_t)N_NODES * 4);
    int*          bsum   = (int*)alloc(SCAN_BLOCKS * 4);
    int*          boff   = (int*)alloc(64 * 4);
    ushort_t*     btK1   = (ushort_t*)alloc((size_t)128 * 512 * 2);
    ushort_t*     btK2   = (ushort_t*)alloc((size_t)128 * 512 * 2);
    float*        part   = (float*)alloc((size_t)DM_BLOCKS * 3 * 4);
    unsigned int* packed = (unsigned int*)alloc((size_t)N_EDGE * 4);
    ushort_t*     x      = (ushort_t*)alloc((size_t)N_NODES * 128 * 2);   // 12.8 MB
    ushort_t*     y      = (ushort_t*)alloc((size_t)N_NODES * 512 * 2);   // 51.2 MB
    // total ~67 MB < proven ws_size >= ~78.8 MB

    hipMemsetAsync(cnt, 0, (size_t)N_NODES * 4 + 256, stream);   // cnt + tickets
    k_prepcnt<<<1 + FILL_B, 256, 0, stream>>>((const ushort_t*)emb, flag, comp1, comp2,
                                              bias1, bias2, rel, ebias, canon, ei, cnt);
    k_scanA<<<SCAN_BLOCKS, 1024, 0, stream>>>(cnt, ptr, bsum, boff, &tick[0]);
    k_scan3<<<SCAN_BLOCKS, 1024, 0, stream>>>(ptr, cursor, boff);
    k_fillinit<<<FILL_B + 512 + X0_B, 256, 0, stream>>>(ei, et, cursor, packed,
                                                        bases1, btK1, bases2, btK2,
                                                        emb, canon, x, flag);

    int ggrid = (N_NODES + 127) / 128;   // 391

    // layer 1: y = gather(comp1 (x) x);  x <- bf16(relu(y@W1 / deg + bias1))
    k_agg2<<<N_NODES / 4, 256, 0, stream>>>(x, ptr, packed, canon + C_COMP1, y);
    k_gemm512<<<ggrid, 256, 0, stream>>>(y, btK1, cnt, canon, x, C_BIAS1, 1);

    // layer 2: y = gather(comp2 (x) x);  x <- bf16(y@W2 / deg + bias2)   (= x2)
    k_agg2<<<N_NODES / 4, 256, 0, stream>>>(x, ptr, packed, canon + C_COMP2, y);
    k_gemm512<<<ggrid, 256, 0, stream>>>(y, btK2, cnt, canon, x, C_BIAS2, 0);

    // decode + loss + fused final
    k_distmultF<<<DM_BLOCKS, 256, 0, stream>>>(x, canon, ei, et, neg, outp, part, &tick[1]);
}

// Round 11
// 282.950 us; speedup vs baseline: 1.8181x; 1.8181x over previous
//
#include <hip/hip_runtime.h>

typedef unsigned short ushort_t;
typedef __attribute__((ext_vector_type(8))) short short8;
typedef __attribute__((ext_vector_type(4))) float f32x4;

#define N_NODES 50000
#define NBASE   4
#define N_EDGE  320000
#define DM_BLOCKS 2048
#define N_GROUPS (N_EDGE / 8)
#define SCAN_BLOCKS 49          // 49*1024 = 50176 >= 50000
#define LDSB_STRIDE 136         // 128 + 8 ushorts pad
#define FILL_B (N_EDGE / 256)   // 1250
#define X0_B   (N_NODES * 128 / 256)

// canonical fp32 small-tensor layout (element offsets)
#define C_COMP1 0
#define C_COMP2 100
#define C_BIAS1 200
#define C_BIAS2 328
#define C_REL   456
#define C_EBIAS 1992
#define C_TOTAL 2120

__device__ __forceinline__ float bf2f(ushort_t u) {
    union { unsigned int i; float f; } v; v.i = ((unsigned int)u) << 16; return v.f;
}
__device__ __forceinline__ ushort_t f2bf(float f) {
    union { float f; unsigned int i; } v; v.f = f;
    unsigned int u = v.i;
    u = (u + 0x7FFFu + ((u >> 16) & 1u)) >> 16;   // RNE
    return (ushort_t)u;
}
__device__ __forceinline__ float readf(const void* p, int i, int isbf) {
    return isbf ? bf2f(((const ushort_t*)p)[i]) : ((const float*)p)[i];
}
__device__ __forceinline__ float softplus(float x) {
    if (x > 20.f) return x;
    if (x < -20.f) return expf(x);
    return log1pf(expf(x));
}

// Fused: block 0 = dtype-detect + canonicalize smalls; blocks >=1 = degree count.
// (no fences -- safe fusion)
__global__ void k_prepcnt(const ushort_t* __restrict__ emb, int* __restrict__ flag,
                          const void* comp1, const void* comp2, const void* b1, const void* b2,
                          const void* rel, const void* eb, float* __restrict__ canon,
                          const int* __restrict__ ei, int* __restrict__ cnt) {
    if (blockIdx.x == 0) {
        __shared__ int c;
        if (threadIdx.x == 0) c = 0;
        __syncthreads();
        int e = (emb[threadIdx.x] >> 7) & 0xFF;
        if (e >= 100 && e <= 126) atomicAdd(&c, 1);
        __syncthreads();
        if (threadIdx.x == 0) *flag = (c >= 200) ? 1 : 0;  // 1 = bf16 inputs
        int isbf = (c >= 200) ? 1 : 0;
        for (int i = threadIdx.x; i < C_TOTAL; i += blockDim.x) {
            float v;
            if      (i < C_COMP2) v = readf(comp1, i - C_COMP1, isbf);
            else if (i < C_BIAS1) v = readf(comp2, i - C_COMP2, isbf);
            else if (i < C_BIAS2) v = readf(b1,    i - C_BIAS1, isbf);
            else if (i < C_REL)   v = readf(b2,    i - C_BIAS2, isbf);
            else if (i < C_EBIAS) v = readf(rel,   i - C_REL,   isbf);
            else                  v = readf(eb,    i - C_EBIAS, isbf);
            canon[i] = v;
        }
    } else {
        int e = (blockIdx.x - 1) * 256 + threadIdx.x;
        if (e < N_EDGE) atomicAdd(&cnt[ei[N_EDGE + e]], 1);
    }
}

// scan stage 1: per-block LDS scan; NO cross-block ticket (fence thrash -- r10 lesson)
__global__ void k_scan1(const int* __restrict__ cnt, int* __restrict__ ptr,
                        int* __restrict__ bsum) {
    __shared__ int s[1024];
    int t = threadIdx.x;
    int i = blockIdx.x * 1024 + t;
    int v = (i < N_NODES) ? cnt[i] : 0;
    s[t] = v;
    __syncthreads();
    for (int off = 1; off < 1024; off <<= 1) {
        int u = (t >= off) ? s[t - off] : 0;
        __syncthreads();
        s[t] += u;
        __syncthreads();
    }
    if (i < N_NODES) ptr[i] = s[t] - v;
    if (t == 1023) bsum[blockIdx.x] = s[1023];
}

__global__ void k_scan2(const int* __restrict__ bsum, int* __restrict__ boff) {
    int t = threadIdx.x;                        // 64
    int v = (t < SCAN_BLOCKS) ? bsum[t] : 0;
    int orig = v;
    #pragma unroll
    for (int off = 1; off < 64; off <<= 1) {
        int u = __shfl_up(v, off);
        if (t >= off) v += u;
    }
    boff[t] = v - orig;
}

__global__ void k_scan3(int* __restrict__ ptr, int* __restrict__ cursor,
                        const int* __restrict__ boff) {
    int t = threadIdx.x;
    int i = blockIdx.x * 1024 + t;
    if (i < N_NODES) {
        int p = ptr[i] + boff[blockIdx.x];
        ptr[i] = p;
        cursor[i] = p;
    }
    if (blockIdx.x == 0 && t == 0) ptr[N_NODES] = N_EDGE;
}

// Fused: blocks [0,FILL_B) = CSR fill; [FILL_B,+512) = repack bases; rest = x0.
__global__ void k_fillinit(const int* __restrict__ ei, const int* __restrict__ et,
                           int* __restrict__ cursor, unsigned int* __restrict__ packed,
                           const void* __restrict__ bases1, ushort_t* __restrict__ btK1,
                           const void* __restrict__ bases2, ushort_t* __restrict__ btK2,
                           const void* __restrict__ emb, const float* __restrict__ canon,
                           ushort_t* __restrict__ x, const int* __restrict__ flag) {
    int bid = blockIdx.x;
    if (bid < FILL_B) {
        int e = bid * 256 + threadIdx.x;
        int dst = ei[N_EDGE + e];
        int pos = atomicAdd(&cursor[dst], 1);
        packed[pos] = (unsigned int)(ei[e] & 0xFFFF) | ((unsigned int)et[e] << 16);
    } else if (bid < FILL_B + 512) {
        int isbf = *flag;
        int rb = bid - FILL_B;
        const void* bases = (rb < 256) ? bases1 : bases2;
        ushort_t* btK = (rb < 256) ? btK1 : btK2;
        int idx = (rb & 255) * 256 + threadIdx.x;
        int b = idx >> 14, i = (idx >> 7) & 127, o = idx & 127;
        btK[(size_t)o * 512 + (b << 7) + i] = f2bf(readf(bases, idx, isbf));
    } else {
        int isbf = *flag;
        int i = (bid - FILL_B - 512) * 256 + threadIdx.x;
        if (i < N_NODES * 128) {
            float v = readf(emb, i, isbf) + canon[C_EBIAS + (i & 127)];
            x[i] = f2bf(fmaxf(v, 0.f));
        }
    }
}

// ---------------- pre-projection aggregate (x-space gather) ----------------
// y[m, b*128+o] = sum_{e in CSR[m]} comp[r_e, b] * x[src_e, o]    (bf16 out)
// ONE WAVE PER NODE, lane owns a packed bf16x2 column pair, 8-edge unroll.
__global__ void k_agg2(const ushort_t* __restrict__ x, const int* __restrict__ ptr,
                       const unsigned int* __restrict__ packed, const float* __restrict__ compf,
                       ushort_t* __restrict__ y) {
    __shared__ float sc[100];
    int tid = threadIdx.x;                  // 256 = 4 waves -> 4 nodes/block
    for (int i = tid; i < 100; i += 256) sc[i] = compf[i];
    __syncthreads();
    int m = blockIdx.x * 4 + (tid >> 6);
    int lane = tid & 63;
    int o2 = lane << 1;
    int beg = ptr[m], end = ptr[m + 1];
    float l0 = 0.f, l1 = 0.f, l2 = 0.f, l3 = 0.f;
    float h0 = 0.f, h1 = 0.f, h2 = 0.f, h3 = 0.f;
    int i = beg;
    for (; i + 8 <= end; i += 8) {
        unsigned int p[8], wv[8];
        #pragma unroll
        for (int j = 0; j < 8; ++j) p[j] = packed[i + j];
        #pragma unroll
        for (int j = 0; j < 8; ++j)
            wv[j] = *(const unsigned int*)(x + (size_t)(p[j] & 0xFFFFu) * 128 + o2);
        #pragma unroll
        for (int j = 0; j < 8; ++j) {
            const float* c = sc + (p[j] >> 16) * 4;
            float vl = bf2f((ushort_t)wv[j]), vh = bf2f((ushort_t)(wv[j] >> 16));
            l0 += c[0] * vl; l1 += c[1] * vl; l2 += c[2] * vl; l3 += c[3] * vl;
            h0 += c[0] * vh; h1 += c[1] * vh; h2 += c[2] * vh; h3 += c[3] * vh;
        }
    }
    for (; i < end; ++i) {
        unsigned int p0 = packed[i];
        unsigned int w0 = *(const unsigned int*)(x + (size_t)(p0 & 0xFFFFu) * 128 + o2);
        const float* c0 = sc + (p0 >> 16) * 4;
        float vl = bf2f((ushort_t)w0), vh = bf2f((ushort_t)(w0 >> 16));
        l0 += c0[0] * vl; l1 += c0[1] * vl; l2 += c0[2] * vl; l3 += c0[3] * vl;
        h0 += c0[0] * vh; h1 += c0[1] * vh; h2 += c0[2] * vh; h3 += c0[3] * vh;
    }
    unsigned int* yp = (unsigned int*)(y + (size_t)m * 512 + o2);
    yp[0]   = (unsigned int)f2bf(l0) | ((unsigned int)f2bf(h0) << 16);
    yp[64]  = (unsigned int)f2bf(l1) | ((unsigned int)f2bf(h1) << 16);
    yp[128] = (unsigned int)f2bf(l2) | ((unsigned int)f2bf(h2) << 16);
    yp[192] = (unsigned int)f2bf(l3) | ((unsigned int)f2bf(h3) << 16);
}

// ---------------- K=512 GEMM: xout = post(y @ W) ----------------
__global__ __launch_bounds__(256) void
k_gemm512(const ushort_t* __restrict__ y, const ushort_t* __restrict__ btK,
          const int* __restrict__ cnt, const float* __restrict__ canon,
          ushort_t* __restrict__ xout, int cbias, int dorelu) {
    __shared__ ushort_t bs[128 * LDSB_STRIDE];    // 34.8 KB
    int tid = threadIdx.x;
    int lane = tid & 63, w = tid >> 6;
    int r = lane & 15, q = lane >> 4;
    int m0 = blockIdx.x * 128;
    f32x4 acc[2][8] = {};
    int row0 = m0 + w * 32 + r;
    int row1 = row0 + 16;
    int cr0 = (row0 < N_NODES) ? row0 : (N_NODES - 1);
    int cr1 = (row1 < N_NODES) ? row1 : (N_NODES - 1);
    const ushort_t* ar0 = y + (size_t)cr0 * 512;
    const ushort_t* ar1 = y + (size_t)cr1 * 512;

    for (int c = 0; c < 4; ++c) {
        __syncthreads();
        {
            int o = tid >> 4;
            int j = (tid & 15) << 3;
            #pragma unroll
            for (int s = 0; s < 8; ++s, o += 16) {
                short8 v = *(const short8*)(btK + (size_t)o * 512 + c * 128 + j);
                *(short8*)(bs + o * LDSB_STRIDE + j) = v;
            }
        }
        __syncthreads();
        #pragma unroll
        for (int ksl = 0; ksl < 4; ++ksl) {
            int k0 = ksl * 32 + q * 8;
            short8 a0 = *(const short8*)(ar0 + c * 128 + k0);
            short8 a1 = *(const short8*)(ar1 + c * 128 + k0);
            #pragma unroll
            for (int t = 0; t < 8; ++t) {
                short8 b = *(const short8*)(bs + (t * 16 + r) * LDSB_STRIDE + k0);
                acc[0][t] = __builtin_amdgcn_mfma_f32_16x16x32_bf16(a0, b, acc[0][t], 0, 0, 0);
                acc[1][t] = __builtin_amdgcn_mfma_f32_16x16x32_bf16(a1, b, acc[1][t], 0, 0, 0);
            }
        }
    }
    #pragma unroll
    for (int i = 0; i < 2; ++i) {
        int rbase = m0 + w * 32 + i * 16 + (q << 2);
        float d[4];
        #pragma unroll
        for (int ii = 0; ii < 4; ++ii) {
            int rr = rbase + ii;
            d[ii] = fmaxf((float)cnt[(rr < N_NODES) ? rr : (N_NODES - 1)], 1.0f);
        }
        #pragma unroll
        for (int t = 0; t < 8; ++t) {
            int col = t * 16 + r;                 // D: col=lane&15, row=quad*4+reg
            float bb = canon[cbias + col];
            #pragma unroll
            for (int ii = 0; ii < 4; ++ii) {
                int rr = rbase + ii;
                if (rr < N_NODES) {
                    float v = acc[i][t][ii] / d[ii] + bb;
                    if (dorelu) v = fmaxf(v, 0.f);
                    xout[(size_t)rr * 128 + col] = f2bf(v);
                }
            }
        }
    }
}

// ---------------- DistMult on bf16 x2: 8 lanes/edge, 8 edges/wave ----------------
// NO cross-block ticket/fence (r10 lesson: per-block __threadfence -> buffer_inv
// L2 invalidation thrash, 6x regression). Separate k_final costs ~3 us.
__global__ void k_distmult8b(const ushort_t* __restrict__ x2, const float* __restrict__ canon,
                             const int* __restrict__ ei, const int* __restrict__ et,
                             const int* __restrict__ neg, float* __restrict__ outp,
                             float* __restrict__ partials) {
    __shared__ float srel[1536];                  // 12 rel x 128, 6 KB
    int tid = threadIdx.x;
    for (int i = tid; i < 1536; i += 256) srel[i] = canon[C_REL + i];
    __syncthreads();
    int lane = tid & 63;
    int g = lane >> 3;
    int l = lane & 7;
    int w = (blockIdx.x * blockDim.x + tid) >> 6;
    int nw = (DM_BLOCKS * 256) >> 6;
    float aL1 = 0.f, aL2 = 0.f, aA = 0.f;
    for (int gid = w; gid < N_GROUPS; gid += nw) {
        int e = gid * 8 + g;
        int h = ei[e], t = ei[N_EDGE + e], r = et[e], qn = neg[e];
        const ushort_t* ph = x2 + (size_t)h * 128 + l * 16;
        const ushort_t* pt = x2 + (size_t)t * 128 + l * 16;
        const ushort_t* pq = x2 + (size_t)qn * 128 + l * 16;
        const float*    pr = srel + r * 128 + l * 16;
        short8 h0 = *(const short8*)ph, h1 = *(const short8*)(ph + 8);
        short8 t0 = *(const short8*)pt, t1 = *(const short8*)(pt + 8);
        short8 q0 = *(const short8*)pq, q1 = *(const short8*)(pq + 8);
        float sp = 0.f, sn = 0.f;
        #pragma unroll
        for (int j = 0; j < 8; ++j) {
            float hv = bf2f(((const ushort_t*)&h0)[j]) * pr[j];
            sp += hv * bf2f(((const ushort_t*)&t0)[j]);
            sn += hv * bf2f(((const ushort_t*)&q0)[j]);
        }
        #pragma unroll
        for (int j = 0; j < 8; ++j) {
            float hv = bf2f(((const ushort_t*)&h1)[j]) * pr[8 + j];
            sp += hv * bf2f(((const ushort_t*)&t1)[j]);
            sn += hv * bf2f(((const ushort_t*)&q1)[j]);
        }
        sp += __shfl_down(sp, 4); sn += __shfl_down(sn, 4);
        sp += __shfl_down(sp, 2); sn += __shfl_down(sn, 2);
        sp += __shfl_down(sp, 1); sn += __shfl_down(sn, 1);
        if (l == 0) {
            outp[e] = sp;
            aL1 += softplus(-sp);
            aL2 += softplus(sn);
            aA  += (sp > sn) ? 1.0f : 0.0f;
        }
    }
    #pragma unroll
    for (int off = 32; off; off >>= 1) {
        aL1 += __shfl_down(aL1, off);
        aL2 += __shfl_down(aL2, off);
        aA  += __shfl_down(aA,  off);
    }
    __shared__ float s[3][4];
    int wl = tid >> 6;
    if (lane == 0) { s[0][wl] = aL1; s[1][wl] = aL2; s[2][wl] = aA; }
    __syncthreads();
    if (tid == 0) {
        float t0 = 0.f, t1 = 0.f, t2 = 0.f;
        for (int i = 0; i < 4; ++i) { t0 += s[0][i]; t1 += s[1][i]; t2 += s[2][i]; }
        partials[blockIdx.x * 3 + 0] = t0;
        partials[blockIdx.x * 3 + 1] = t1;
        partials[blockIdx.x * 3 + 2] = t2;
    }
}

__global__ void k_final(const float* __restrict__ partials, float* __restrict__ outp) {
    __shared__ float s[3][256];
    int tid = threadIdx.x;
    float t0 = 0.f, t1 = 0.f, t2 = 0.f;
    for (int i = tid; i < DM_BLOCKS; i += 256) {
        t0 += partials[i * 3 + 0];
        t1 += partials[i * 3 + 1];
        t2 += partials[i * 3 + 2];
    }
    s[0][tid] = t0; s[1][tid] = t1; s[2][tid] = t2;
    __syncthreads();
    for (int st = 128; st; st >>= 1) {
        if (tid < st) {
            s[0][tid] += s[0][tid + st];
            s[1][tid] += s[1][tid + st];
            s[2][tid] += s[2][tid + st];
        }
        __syncthreads();
    }
    if (tid == 0) {
        float inv = 1.0f / (float)N_EDGE;
        outp[N_EDGE]     = 0.5f * (s[0][0] * inv + s[1][0] * inv);
        outp[N_EDGE + 1] = s[2][0] * inv;
    }
}

extern "C" void kernel_launch(void* const* d_in, const int* in_sizes, int n_in,
                              void* d_out, int out_size, void* d_ws, size_t ws_size,
                              hipStream_t stream) {
    const void* emb    = d_in[0];
    const void* ebias  = d_in[1];
    const void* bases1 = d_in[2];
    const void* comp1  = d_in[3];
    const void* bias1  = d_in[4];
    const void* bases2 = d_in[5];
    const void* comp2  = d_in[6];
    const void* bias2  = d_in[7];
    const void* rel    = d_in[8];
    const int*  ei     = (const int*)d_in[9];
    const int*  et     = (const int*)d_in[10];
    const int*  neg    = (const int*)d_in[11];
    float*      outp   = (float*)d_out;

    char* ws = (char*)d_ws;
    size_t off = 0;
    auto alloc = [&](size_t bytes) { char* p = ws + off; off += (bytes + 255) & ~(size_t)255; return p; };
    int*          flag   = (int*)alloc(256);
    float*        canon  = (float*)alloc((size_t)C_TOTAL * 4);
    int*          cnt    = (int*)alloc((size_t)N_NODES * 4);
    int*          ptr    = (int*)alloc((size_t)(N_NODES + 1) * 4);
    int*          cursor = (int*)alloc((size_t)N_NODES * 4);
    int*          bsum   = (int*)alloc(SCAN_BLOCKS * 4);
    int*          boff   = (int*)alloc(64 * 4);
    ushort_t*     btK1   = (ushort_t*)alloc((size_t)128 * 512 * 2);
    ushort_t*     btK2   = (ushort_t*)alloc((size_t)128 * 512 * 2);
    float*        part   = (float*)alloc((size_t)DM_BLOCKS * 3 * 4);
    unsigned int* packed = (unsigned int*)alloc((size_t)N_EDGE * 4);
    ushort_t*     x      = (ushort_t*)alloc((size_t)N_NODES * 128 * 2);   // 12.8 MB
    ushort_t*     y      = (ushort_t*)alloc((size_t)N_NODES * 512 * 2);   // 51.2 MB
    // total ~67 MB < proven ws_size >= ~78.8 MB

    hipMemsetAsync(cnt, 0, (size_t)N_NODES * 4, stream);
    k_prepcnt<<<1 + FILL_B, 256, 0, stream>>>((const ushort_t*)emb, flag, comp1, comp2,
                                              bias1, bias2, rel, ebias, canon, ei, cnt);
    k_scan1<<<SCAN_BLOCKS, 1024, 0, stream>>>(cnt, ptr, bsum);
    k_scan2<<<1, 64, 0, stream>>>(bsum, boff);
    k_scan3<<<SCAN_BLOCKS, 1024, 0, stream>>>(ptr, cursor, boff);
    k_fillinit<<<FILL_B + 512 + X0_B, 256, 0, stream>>>(ei, et, cursor, packed,
                                                        bases1, btK1, bases2, btK2,
                                                        emb, canon, x, flag);

    int ggrid = (N_NODES + 127) / 128;   // 391

    // layer 1: y = gather(comp1 (x) x);  x <- bf16(relu(y@W1 / deg + bias1))
    k_agg2<<<N_NODES / 4, 256, 0, stream>>>(x, ptr, packed, canon + C_COMP1, y);
    k_gemm512<<<ggrid, 256, 0, stream>>>(y, btK1, cnt, canon, x, C_BIAS1, 1);

    // layer 2: y = gather(comp2 (x) x);  x <- bf16(y@W2 / deg + bias2)   (= x2)
    k_agg2<<<N_NODES / 4, 256, 0, stream>>>(x, ptr, packed, canon + C_COMP2, y);
    k_gemm512<<<ggrid, 256, 0, stream>>>(y, btK2, cnt, canon, x, C_BIAS2, 0);

    // decode + loss (separate final -- kernel boundary provides the ordering)
    k_distmult8b<<<DM_BLOCKS, 256, 0, stream>>>(x, canon, ei, et, neg, outp, part);
    k_final<<<1, 256, 0, stream>>>(part, outp);
}